// Round 3
// baseline (2292.418 us; speedup 1.0000x reference)
//
#include <hip/hip_runtime.h>
#include <hip/hip_bf16.h>

#define NN 30000
#define NE 480000

typedef __attribute__((ext_vector_type(8))) short short8;
typedef __attribute__((ext_vector_type(4))) float floatx4;

__device__ __forceinline__ float bf2f(__hip_bfloat16 h) { return __bfloat162float(h); }

__device__ __forceinline__ short2 split_bf16(float f) {
    __hip_bfloat16 h = __float2bfloat16(f);          // RTNE high part
    float r = f - __bfloat162float(h);               // residual, |r| <= 2^-9 |f|
    __hip_bfloat16 l = __float2bfloat16(r);
    short2 out;
    out.x = *reinterpret_cast<short*>(&h);
    out.y = *reinterpret_cast<short*>(&l);
    return out;
}

// ---- GEMM: C[M,N] = A[M,K] @ W[K,N] + bias (+res). fp32 in/out, split-bf16 MFMA (error ~2^-17).
// One 16x16 tile per wave. M multiple of 16.
template<int K, int N, bool OUT_BF16EA>
__launch_bounds__(256)
__global__ void gemm_mfma(const float* __restrict__ A, const float* __restrict__ W,
                          const float* __restrict__ bias, const float* __restrict__ res,
                          void* __restrict__ Cv, int total_waves)
{
    int wave = ((blockIdx.x * 256) + threadIdx.x) >> 6;
    if (wave >= total_waves) return;
    constexpr int NT = (N + 15) / 16;
    const int mt = wave / NT, nt = wave % NT;
    const int lane = threadIdx.x & 63;
    const int l15 = lane & 15, quad = lane >> 4;
    const int row = mt * 16 + l15;   // A row this lane loads (A frag: m=lane&15, k=quad*8+j)
    const int col = nt * 16 + l15;   // B/C column this lane owns
    floatx4 acc = {0.f, 0.f, 0.f, 0.f};
#pragma unroll
    for (int k0 = 0; k0 < K; k0 += 32) {
        const int kb = k0 + quad * 8;
        short8 ah, al, bh, bl;
        if constexpr (K % 32 == 0) {
            const float* ap = A + (size_t)row * K + kb;
            floatx4 a0 = *(const floatx4*)ap;
            floatx4 a1 = *(const floatx4*)(ap + 4);
#pragma unroll
            for (int j = 0; j < 4; j++) {
                short2 s0 = split_bf16(a0[j]); ah[j] = s0.x; al[j] = s0.y;
                short2 s1 = split_bf16(a1[j]); ah[j + 4] = s1.x; al[j + 4] = s1.y;
            }
        } else {
#pragma unroll
            for (int j = 0; j < 8; j++) {
                int kk = kb + j;
                float v = (kk < K) ? A[(size_t)row * K + kk] : 0.f;
                short2 s = split_bf16(v); ah[j] = s.x; al[j] = s.y;
            }
        }
#pragma unroll
        for (int j = 0; j < 8; j++) {
            int kk = kb + j;
            float v = ((kk < K) && (col < N)) ? W[(size_t)kk * N + col] : 0.f;
            short2 s = split_bf16(v); bh[j] = s.x; bl[j] = s.y;
        }
        acc = __builtin_amdgcn_mfma_f32_16x16x32_bf16(ah, bh, acc, 0, 0, 0);
        acc = __builtin_amdgcn_mfma_f32_16x16x32_bf16(al, bh, acc, 0, 0, 0);
        acc = __builtin_amdgcn_mfma_f32_16x16x32_bf16(ah, bl, acc, 0, 0, 0);
    }
    if (col < N) {
        float bv = bias[col];
#pragma unroll
        for (int r = 0; r < 4; r++) {
            int ro = mt * 16 + quad * 4 + r;   // C/D: col=lane&15, row=quad*4+reg (m89-verified)
            float v = acc[r] + bv;
            if (res) v += res[(size_t)ro * N + col];
            if constexpr (OUT_BF16EA) ((__hip_bfloat16*)Cv)[(size_t)ro * N + col] = __float2bfloat16(v);
            else ((float*)Cv)[(size_t)ro * N + col] = v;
        }
    }
}

// ---- relu(LayerNorm(x)*g+b), one wave per node ----
template<int H>
__launch_bounds__(256)
__global__ void relu_ln_kernel(const float* __restrict__ X, const float* __restrict__ g,
                               const float* __restrict__ b, float* __restrict__ Y)
{
    constexpr int V = H / 64;
    int node = (blockIdx.x * 256 + threadIdx.x) >> 6;
    int lane = threadIdx.x & 63;
    if (node >= NN) return;
    const float* xr = X + (size_t)node * H + lane * V;
    float v[V];
#pragma unroll
    for (int i = 0; i < V; i++) v[i] = xr[i];
    float sm = 0.f;
#pragma unroll
    for (int i = 0; i < V; i++) sm += v[i];
#pragma unroll
    for (int m = 32; m; m >>= 1) sm += __shfl_xor(sm, m, 64);
    float mean = sm * (1.0f / H);
    float vs = 0.f;
#pragma unroll
    for (int i = 0; i < V; i++) { float d = v[i] - mean; vs += d * d; }
#pragma unroll
    for (int m = 32; m; m >>= 1) vs += __shfl_xor(vs, m, 64);
    float rs = rsqrtf(vs * (1.0f / H) + 1e-5f);
    float* yr = Y + (size_t)node * H + lane * V;
#pragma unroll
    for (int i = 0; i < V; i++) {
        int c = lane * V + i;
        float y = (v[i] - mean) * rs * g[c] + b[c];
        yr[i] = fmaxf(y, 0.f);
    }
}

// ---- zero fill (float4) ----
__global__ void zero_kernel(float* __restrict__ p, int n4)
{
    int i = blockIdx.x * 256 + threadIdx.x;
    if (i < n4) ((float4*)p)[i] = make_float4(0.f, 0.f, 0.f, 0.f);
}

// ---- edge pass 1: atomicMax of logits per (dst, f); float -> ordered uint key, init 0 ----
__launch_bounds__(256)
__global__ void edge_max_kernel(const float* __restrict__ hin, const __hip_bfloat16* __restrict__ ea,
                                const int* __restrict__ src, const int* __restrict__ dst,
                                const float* __restrict__ tptr, int layer,
                                unsigned* __restrict__ mxk)
{
    int idx = blockIdx.x * 256 + threadIdx.x;   // exactly NE*128 threads
    int e = idx >> 7, f = idx & 127;
    float tt = tptr[layer];
    float m = fmaxf(hin[(size_t)src[e] * 128 + f] + bf2f(ea[idx]), 0.f) + 1e-7f;
    unsigned u = __float_as_uint(m * tt);
    unsigned key = u ^ (unsigned)(((int)u >> 31) | 0x80000000);
    atomicMax(mxk + (size_t)dst[e] * 128 + f, key);
}

// ---- edge pass 2: accumulate sum(exp) and sum(msg*exp) ----
__launch_bounds__(256)
__global__ void edge_sum_kernel(const float* __restrict__ hin, const __hip_bfloat16* __restrict__ ea,
                                const int* __restrict__ src, const int* __restrict__ dst,
                                const float* __restrict__ tptr, int layer,
                                const unsigned* __restrict__ mxk,
                                float* __restrict__ sden, float* __restrict__ num)
{
    int idx = blockIdx.x * 256 + threadIdx.x;
    int e = idx >> 7, f = idx & 127;
    float tt = tptr[layer];
    float m = fmaxf(hin[(size_t)src[e] * 128 + f] + bf2f(ea[idx]), 0.f) + 1e-7f;
    float lg = m * tt;
    size_t o = (size_t)dst[e] * 128 + f;
    unsigned key = mxk[o];
    unsigned u = (key & 0x80000000u) ? (key ^ 0x80000000u) : ~key;
    float mx = __uint_as_float(u);
    float ex = __expf(lg - mx);
    atomicAdd(sden + o, ex);
    atomicAdd(num + o, m * ex);
}

// ---- z = num/(s+eps) + hin ----
__global__ void combine_kernel(const float4* __restrict__ num, const float4* __restrict__ s,
                               const float4* __restrict__ hin, float4* __restrict__ z)
{
    int i = blockIdx.x * 256 + threadIdx.x;   // NN*32 exactly
    float4 n4 = num[i], s4 = s[i], h4 = hin[i];
    float4 o;
    o.x = n4.x / (s4.x + 1e-16f) + h4.x;
    o.y = n4.y / (s4.y + 1e-16f) + h4.y;
    o.z = n4.z / (s4.z + 1e-16f) + h4.z;
    o.w = n4.w / (s4.w + 1e-16f) + h4.w;
    z[i] = o;
}

extern "C" void kernel_launch(void* const* d_in, const int* in_sizes, int n_in,
                              void* d_out, int out_size, void* d_ws, size_t ws_size,
                              hipStream_t stream)
{
    const float* x         = (const float*)d_in[0];
    const float* edge_attr = (const float*)d_in[1];
    const float* nw        = (const float*)d_in[2];
    const float* nb        = (const float*)d_in[3];
    const float* ew        = (const float*)d_in[4];
    const float* eb        = (const float*)d_in[5];
    const float* m1w       = (const float*)d_in[6];
    const float* m1b       = (const float*)d_in[7];
    const float* lng       = (const float*)d_in[8];
    const float* lnb       = (const float*)d_in[9];
    const float* m2w       = (const float*)d_in[10];
    const float* m2b       = (const float*)d_in[11];
    const float* tpr       = (const float*)d_in[12];
    const float* ng        = (const float*)d_in[13];
    const float* nbb       = (const float*)d_in[14];
    const float* lw        = (const float*)d_in[15];
    const float* lb        = (const float*)d_in[16];
    const int* ei  = (const int*)d_in[17];
    const int* src = ei;
    const int* dst = ei + NE;

    // workspace carve (~180 MB used)
    char* w = (char*)d_ws;
    __hip_bfloat16* ea = (__hip_bfloat16*)w; w += (size_t)NE * 128 * 2;   // 122.88 MB
    float* hA  = (float*)w; w += (size_t)NN * 128 * 4;
    float* hB  = (float*)w; w += (size_t)NN * 128 * 4;
    float* hin = (float*)w; w += (size_t)NN * 128 * 4;
    unsigned* mx = (unsigned*)w;              // mx aliases zbuf (mx dead before combine writes zbuf)
    float* zbuf  = (float*)w; w += (size_t)NN * 128 * 4;
    float* sden  = (float*)w; w += (size_t)NN * 128 * 4;   // contiguous with zbuf
    float* num   = (float*)w; w += (size_t)NN * 128 * 4;   // contiguous with sden
    float* z1    = sden;     // [30000,256] aliases sden+num (dead after combine; z1 live after)

    // encoders
    gemm_mfma<16, 128, true ><<<(NE / 16) * 8 / 4, 256, 0, stream>>>(edge_attr, ew, eb, nullptr, ea, (NE / 16) * 8);
    gemm_mfma<64, 128, false><<<(NN / 16) * 8 / 4, 256, 0, stream>>>(x, nw, nb, nullptr, hA, (NN / 16) * 8);

    float* h = hA; float* hn = hB;
    for (int layer = 0; layer < 3; ++layer) {
        const float* hi;
        if (layer == 0) {
            hi = h;
        } else {
            relu_ln_kernel<128><<<NN / 4, 256, 0, stream>>>(h, ng + layer * 128, nbb + layer * 128, hin);
            hi = hin;
        }
        zero_kernel<<<(NN * 128 * 3 / 4) / 256, 256, 0, stream>>>((float*)mx, NN * 128 * 3 / 4);
        edge_max_kernel<<<NE * 128 / 256, 256, 0, stream>>>(hi, ea, src, dst, tpr, layer, mx);
        edge_sum_kernel<<<NE * 128 / 256, 256, 0, stream>>>(hi, ea, src, dst, tpr, layer, mx, sden, num);
        combine_kernel<<<NN * 32 / 256, 256, 0, stream>>>((const float4*)num, (const float4*)sden,
                                                          (const float4*)hi, (float4*)zbuf);
        gemm_mfma<128, 256, false><<<(NN / 16) * 16 / 4, 256, 0, stream>>>(
            zbuf, m1w + (size_t)layer * 128 * 256, m1b + layer * 256, nullptr, z1, (NN / 16) * 16);
        relu_ln_kernel<256><<<NN / 4, 256, 0, stream>>>(z1, lng + layer * 256, lnb + layer * 256, z1);
        gemm_mfma<256, 128, false><<<(NN / 16) * 8 / 4, 256, 0, stream>>>(
            z1, m2w + (size_t)layer * 256 * 128, m2b + layer * 128, (layer > 0) ? h : nullptr, hn, (NN / 16) * 8);
        float* tmp = h; h = hn; hn = tmp;
    }
    // final norm (layer-0 params) + classifier
    relu_ln_kernel<128><<<NN / 4, 256, 0, stream>>>(h, ng, nbb, hin);
    gemm_mfma<128, 10, false><<<(NN / 16 + 3) / 4, 256, 0, stream>>>(
        hin, lw, lb, nullptr, d_out, NN / 16);
}

// Round 4
// 832.009 us; speedup vs baseline: 2.7553x; 2.7553x over previous
//
#include <hip/hip_runtime.h>
#include <hip/hip_bf16.h>

#define NN 30000
#define NE 480000

typedef __attribute__((ext_vector_type(8))) short short8;
typedef __attribute__((ext_vector_type(4))) float floatx4;

__device__ __forceinline__ float bf2f(__hip_bfloat16 h) { return __bfloat162float(h); }

__device__ __forceinline__ short2 split_bf16(float f) {
    __hip_bfloat16 h = __float2bfloat16(f);          // RTNE high part
    float r = f - __bfloat162float(h);               // residual, |r| <= 2^-9 |f|
    __hip_bfloat16 l = __float2bfloat16(r);
    short2 out;
    out.x = *reinterpret_cast<short*>(&h);
    out.y = *reinterpret_cast<short*>(&l);
    return out;
}

// ---- GEMM: C[M,N] = A[M,K] @ W[K,N] + bias (+res). fp32 in/out, split-bf16 MFMA (error ~2^-17).
template<int K, int N, bool OUT_BF16EA>
__launch_bounds__(256)
__global__ void gemm_mfma(const float* __restrict__ A, const float* __restrict__ W,
                          const float* __restrict__ bias, const float* __restrict__ res,
                          void* __restrict__ Cv, int total_waves)
{
    int wave = ((blockIdx.x * 256) + threadIdx.x) >> 6;
    if (wave >= total_waves) return;
    constexpr int NT = (N + 15) / 16;
    const int mt = wave / NT, nt = wave % NT;
    const int lane = threadIdx.x & 63;
    const int l15 = lane & 15, quad = lane >> 4;
    const int row = mt * 16 + l15;
    const int col = nt * 16 + l15;
    floatx4 acc = {0.f, 0.f, 0.f, 0.f};
#pragma unroll
    for (int k0 = 0; k0 < K; k0 += 32) {
        const int kb = k0 + quad * 8;
        short8 ah, al, bh, bl;
        if constexpr (K % 32 == 0) {
            const float* ap = A + (size_t)row * K + kb;
            floatx4 a0 = *(const floatx4*)ap;
            floatx4 a1 = *(const floatx4*)(ap + 4);
#pragma unroll
            for (int j = 0; j < 4; j++) {
                short2 s0 = split_bf16(a0[j]); ah[j] = s0.x; al[j] = s0.y;
                short2 s1 = split_bf16(a1[j]); ah[j + 4] = s1.x; al[j + 4] = s1.y;
            }
        } else {
#pragma unroll
            for (int j = 0; j < 8; j++) {
                int kk = kb + j;
                float v = (kk < K) ? A[(size_t)row * K + kk] : 0.f;
                short2 s = split_bf16(v); ah[j] = s.x; al[j] = s.y;
            }
        }
#pragma unroll
        for (int j = 0; j < 8; j++) {
            int kk = kb + j;
            float v = ((kk < K) && (col < N)) ? W[(size_t)kk * N + col] : 0.f;
            short2 s = split_bf16(v); bh[j] = s.x; bl[j] = s.y;
        }
        acc = __builtin_amdgcn_mfma_f32_16x16x32_bf16(ah, bh, acc, 0, 0, 0);
        acc = __builtin_amdgcn_mfma_f32_16x16x32_bf16(al, bh, acc, 0, 0, 0);
        acc = __builtin_amdgcn_mfma_f32_16x16x32_bf16(ah, bl, acc, 0, 0, 0);
    }
    if (col < N) {
        float bv = bias[col];
#pragma unroll
        for (int r = 0; r < 4; r++) {
            int ro = mt * 16 + quad * 4 + r;   // C/D: col=lane&15, row=quad*4+reg
            float v = acc[r] + bv;
            if (res) v += res[(size_t)ro * N + col];
            if constexpr (OUT_BF16EA) ((__hip_bfloat16*)Cv)[(size_t)ro * N + col] = __float2bfloat16(v);
            else ((float*)Cv)[(size_t)ro * N + col] = v;
        }
    }
}

// ---- relu(LayerNorm(x)*g+b), one wave per node ----
template<int H>
__launch_bounds__(256)
__global__ void relu_ln_kernel(const float* __restrict__ X, const float* __restrict__ g,
                               const float* __restrict__ b, float* __restrict__ Y)
{
    constexpr int V = H / 64;
    int node = (blockIdx.x * 256 + threadIdx.x) >> 6;
    int lane = threadIdx.x & 63;
    if (node >= NN) return;
    const float* xr = X + (size_t)node * H + lane * V;
    float v[V];
#pragma unroll
    for (int i = 0; i < V; i++) v[i] = xr[i];
    float sm = 0.f;
#pragma unroll
    for (int i = 0; i < V; i++) sm += v[i];
#pragma unroll
    for (int m = 32; m; m >>= 1) sm += __shfl_xor(sm, m, 64);
    float mean = sm * (1.0f / H);
    float vs = 0.f;
#pragma unroll
    for (int i = 0; i < V; i++) { float d = v[i] - mean; vs += d * d; }
#pragma unroll
    for (int m = 32; m; m >>= 1) vs += __shfl_xor(vs, m, 64);
    float rs = rsqrtf(vs * (1.0f / H) + 1e-5f);
    float* yr = Y + (size_t)node * H + lane * V;
#pragma unroll
    for (int i = 0; i < V; i++) {
        int c = lane * V + i;
        float y = (v[i] - mean) * rs * g[c] + b[c];
        yr[i] = fmaxf(y, 0.f);
    }
}

// ---- zero fill ----
__global__ void zero_kernel(int* __restrict__ p, int n)
{
    int i = blockIdx.x * 256 + threadIdx.x;
    if (i < n) p[i] = 0;
}

// ---- CSR build: histogram of dst ----
__global__ void hist_kernel(const int* __restrict__ dst, int* __restrict__ count)
{
    int e = blockIdx.x * 256 + threadIdx.x;
    if (e < NE) atomicAdd(count + dst[e], 1);
}

// ---- CSR build: single-block exclusive scan of count[NN] -> rowptr[NN+1] ----
__launch_bounds__(1024)
__global__ void scan_kernel(const int* __restrict__ count, int* __restrict__ rowptr)
{
    __shared__ int part[1024];
    const int t = threadIdx.x;
    const int CH = (NN + 1023) / 1024;          // 30
    const int base = t * CH;
    int sum = 0;
    for (int j = 0; j < CH; j++) {
        int idx = base + j;
        if (idx < NN) sum += count[idx];
    }
    part[t] = sum;
    __syncthreads();
    for (int d = 1; d < 1024; d <<= 1) {
        int v = (t >= d) ? part[t - d] : 0;
        __syncthreads();
        part[t] += v;
        __syncthreads();
    }
    int off = (t == 0) ? 0 : part[t - 1];
    for (int j = 0; j < CH; j++) {
        int idx = base + j;
        if (idx < NN) { rowptr[idx] = off; off += count[idx]; }
    }
    if (t == 1023) rowptr[NN] = part[1023];
}

// ---- CSR build: scatter edge ids into buckets ----
__global__ void scatter_kernel(const int* __restrict__ dst, const int* __restrict__ rowptr,
                               int* __restrict__ cursor, int* __restrict__ eidx)
{
    int e = blockIdx.x * 256 + threadIdx.x;
    if (e < NE) {
        int d = dst[e];
        int r = atomicAdd(cursor + d, 1);
        eidx[rowptr[d] + r] = e;
    }
}

// ---- fused aggregation: online softmax over incoming edges, one wave per node ----
// out = sum(msg*alpha) + hin   (combine fused)
__device__ __forceinline__ void online_upd(float hv, unsigned abits, float tt,
                                           float& m, float& s, float& n)
{
    float a = __uint_as_float(abits);
    float g = fmaxf(hv + a, 0.f) + 1e-7f;     // msg
    float l = g * tt;                          // logit
    float nm = fmaxf(m, l);
    float c = __expf(m - nm);
    float d = __expf(l - nm);
    s = s * c + d;
    n = n * c + g * d;
    m = nm;
}

__launch_bounds__(256)
__global__ void agg_kernel(const float* __restrict__ hin, const __hip_bfloat16* __restrict__ ea,
                           const int* __restrict__ src, const int* __restrict__ eidx,
                           const int* __restrict__ rowptr, const float* __restrict__ tptr,
                           int layer, float* __restrict__ zout)
{
    int node = (blockIdx.x * 256 + threadIdx.x) >> 6;
    if (node >= NN) return;
    const int lane = threadIdx.x & 63;
    const float tt = tptr[layer];
    const unsigned* eau = (const unsigned*)ea;          // packed bf16x2
    const float2* h2 = (const float2*)hin;
    int i = rowptr[node];
    const int end = rowptr[node + 1];
    float m0 = -1e30f, m1 = -1e30f, s0 = 0.f, s1 = 0.f, n0 = 0.f, n1 = 0.f;
    for (; i + 2 <= end; i += 2) {
        int e0 = eidx[i], e1 = eidx[i + 1];
        int sn0 = src[e0], sn1 = src[e1];
        float2 hv0 = h2[(size_t)sn0 * 64 + lane];
        float2 hv1 = h2[(size_t)sn1 * 64 + lane];
        unsigned u0 = eau[(size_t)e0 * 64 + lane];
        unsigned u1 = eau[(size_t)e1 * 64 + lane];
        online_upd(hv0.x, u0 << 16, tt, m0, s0, n0);
        online_upd(hv0.y, u0 & 0xffff0000u, tt, m1, s1, n1);
        online_upd(hv1.x, u1 << 16, tt, m0, s0, n0);
        online_upd(hv1.y, u1 & 0xffff0000u, tt, m1, s1, n1);
    }
    if (i < end) {
        int e0 = eidx[i];
        int sn0 = src[e0];
        float2 hv0 = h2[(size_t)sn0 * 64 + lane];
        unsigned u0 = eau[(size_t)e0 * 64 + lane];
        online_upd(hv0.x, u0 << 16, tt, m0, s0, n0);
        online_upd(hv0.y, u0 & 0xffff0000u, tt, m1, s1, n1);
    }
    float2 res = h2[(size_t)node * 64 + lane];
    float2 o;
    o.x = n0 / (s0 + 1e-16f) + res.x;
    o.y = n1 / (s1 + 1e-16f) + res.y;
    ((float2*)zout)[(size_t)node * 64 + lane] = o;
}

extern "C" void kernel_launch(void* const* d_in, const int* in_sizes, int n_in,
                              void* d_out, int out_size, void* d_ws, size_t ws_size,
                              hipStream_t stream)
{
    const float* x         = (const float*)d_in[0];
    const float* edge_attr = (const float*)d_in[1];
    const float* nw        = (const float*)d_in[2];
    const float* nb        = (const float*)d_in[3];
    const float* ew        = (const float*)d_in[4];
    const float* eb        = (const float*)d_in[5];
    const float* m1w       = (const float*)d_in[6];
    const float* m1b       = (const float*)d_in[7];
    const float* lng       = (const float*)d_in[8];
    const float* lnb       = (const float*)d_in[9];
    const float* m2w       = (const float*)d_in[10];
    const float* m2b       = (const float*)d_in[11];
    const float* tpr       = (const float*)d_in[12];
    const float* ng        = (const float*)d_in[13];
    const float* nbb       = (const float*)d_in[14];
    const float* lw        = (const float*)d_in[15];
    const float* lb        = (const float*)d_in[16];
    const int* ei  = (const int*)d_in[17];
    const int* src = ei;
    const int* dst = ei + NE;

    // workspace carve
    char* w = (char*)d_ws;
    __hip_bfloat16* ea = (__hip_bfloat16*)w; w += (size_t)NE * 128 * 2;   // 122.88 MB
    float* hA   = (float*)w; w += (size_t)NN * 128 * 4;
    float* hB   = (float*)w; w += (size_t)NN * 128 * 4;
    float* hin  = (float*)w; w += (size_t)NN * 128 * 4;
    float* zbuf = (float*)w; w += (size_t)NN * 128 * 4;
    float* z1   = (float*)w; w += (size_t)NN * 256 * 4;
    int* count  = (int*)w;   w += (size_t)NN * 4;
    int* cursor = (int*)w;   w += (size_t)NN * 4;
    int* rowptr = (int*)w;   w += (size_t)(NN + 1) * 4;
    int* eidx   = (int*)w;   w += (size_t)NE * 4;

    // ---- CSR build (once; reused by all 3 layers) ----
    zero_kernel<<<(2 * NN + 255) / 256, 256, 0, stream>>>(count, 2 * NN);  // count+cursor contiguous
    hist_kernel<<<(NE + 255) / 256, 256, 0, stream>>>(dst, count);
    scan_kernel<<<1, 1024, 0, stream>>>(count, rowptr);
    scatter_kernel<<<(NE + 255) / 256, 256, 0, stream>>>(dst, rowptr, cursor, eidx);

    // ---- encoders ----
    gemm_mfma<16, 128, true ><<<(NE / 16) * 8 / 4, 256, 0, stream>>>(edge_attr, ew, eb, nullptr, ea, (NE / 16) * 8);
    gemm_mfma<64, 128, false><<<(NN / 16) * 8 / 4, 256, 0, stream>>>(x, nw, nb, nullptr, hA, (NN / 16) * 8);

    float* h = hA; float* hn = hB;
    for (int layer = 0; layer < 3; ++layer) {
        const float* hi;
        if (layer == 0) {
            hi = h;
        } else {
            relu_ln_kernel<128><<<NN / 4, 256, 0, stream>>>(h, ng + layer * 128, nbb + layer * 128, hin);
            hi = hin;
        }
        agg_kernel<<<(NN + 3) / 4, 256, 0, stream>>>(hi, ea, src, eidx, rowptr, tpr, layer, zbuf);
        gemm_mfma<128, 256, false><<<(NN / 16) * 16 / 4, 256, 0, stream>>>(
            zbuf, m1w + (size_t)layer * 128 * 256, m1b + layer * 256, nullptr, z1, (NN / 16) * 16);
        relu_ln_kernel<256><<<NN / 4, 256, 0, stream>>>(z1, lng + layer * 256, lnb + layer * 256, z1);
        gemm_mfma<256, 128, false><<<(NN / 16) * 8 / 4, 256, 0, stream>>>(
            z1, m2w + (size_t)layer * 256 * 128, m2b + layer * 128, (layer > 0) ? h : nullptr, hn, (NN / 16) * 8);
        float* tmp = h; h = hn; hn = tmp;
    }
    // final norm (layer-0 params) + classifier
    relu_ln_kernel<128><<<NN / 4, 256, 0, stream>>>(h, ng, nbb, hin);
    gemm_mfma<128, 10, false><<<(NN / 16 + 3) / 4, 256, 0, stream>>>(
        hin, lw, lb, nullptr, d_out, NN / 16);
}